// Round 5
// baseline (495.825 us; speedup 1.0000x reference)
//
#include <hip/hip_runtime.h>
#include <hip/hip_bf16.h>

#define DEV __device__ __forceinline__

typedef __attribute__((ext_vector_type(8))) short bf16x8;
typedef __attribute__((ext_vector_type(4))) float f32x4;
typedef __attribute__((ext_vector_type(8))) unsigned short u16x8;

DEV unsigned short f2bf(float f){
  unsigned int b = __float_as_uint(f);
  return (unsigned short)((b + 0x7fffu + ((b >> 16) & 1u)) >> 16);
}
DEV float bf2f(unsigned short u){ return __uint_as_float(((unsigned int)u)<<16); }

DEV float silu_f(float v){ return v / (1.f + __expf(-v)); }

DEV void gl_lds16(const void* g, void* l){
  __builtin_amdgcn_global_load_lds((const __attribute__((address_space(1))) void*)g,
                                   (__attribute__((address_space(3))) void*)l, 16, 0, 0);
}

// ---------------- LayerNorm rows: fp32 in -> bf16 out ----------------
__global__ __launch_bounds__(256) void ln_rows(const float* __restrict__ x,
    const float* __restrict__ g, const float* __restrict__ bt,
    unsigned short* __restrict__ out, int D, int nvec)
{
  int row = blockIdx.x, t = threadIdx.x;
  const float4* xr = (const float4*)(x + (size_t)row * D);
  float4 v = make_float4(0.f,0.f,0.f,0.f);
  if (t < nvec) v = xr[t];
  float s  = v.x+v.y+v.z+v.w;
  float s2 = v.x*v.x+v.y*v.y+v.z*v.z+v.w*v.w;
  #pragma unroll
  for (int o=32;o;o>>=1){ s += __shfl_down(s,o,64); s2 += __shfl_down(s2,o,64); }
  __shared__ float red[8];
  if ((t&63)==0){ red[t>>6]=s; red[4+(t>>6)]=s2; }
  __syncthreads();
  float fs  = red[0]+red[1]+red[2]+red[3];
  float fs2 = red[4]+red[5]+red[6]+red[7];
  float mean = fs / (float)D;
  float var  = fmaxf(fs2/(float)D - mean*mean, 0.f);
  float rstd = rsqrtf(var + 1e-5f);
  if (t < nvec){
    float4 gv = ((const float4*)g)[t];
    float4 bv = ((const float4*)bt)[t];
    ushort4 o4;
    o4.x = f2bf((v.x-mean)*rstd*gv.x + bv.x);
    o4.y = f2bf((v.y-mean)*rstd*gv.y + bv.y);
    o4.z = f2bf((v.z-mean)*rstd*gv.z + bv.z);
    o4.w = f2bf((v.w-mean)*rstd*gv.w + bv.w);
    *(ushort4*)(out + (size_t)row*D + t*4) = o4;
  }
}

// ---------------- weight convert + transpose: W[K][N] fp32 -> Wt[N][K] bf16 ----
__global__ __launch_bounds__(256) void wconv(const float* __restrict__ W,
    unsigned short* __restrict__ Wt, int K, int N)
{
  __shared__ float tile[32][33];
  int n0 = blockIdx.x<<5, k0 = blockIdx.y<<5;
  int tx = threadIdx.x & 31, ty = threadIdx.x >> 5;
  #pragma unroll
  for (int i=0;i<4;i++)
    tile[ty + i*8][tx] = W[(size_t)(k0 + ty + i*8)*N + n0 + tx];
  __syncthreads();
  #pragma unroll
  for (int i=0;i<4;i++)
    Wt[(size_t)(n0 + ty + i*8)*K + k0 + tx] = f2bf(tile[tx][ty + i*8]);
}

// ---------------- bias concat ------------------------------------------------
__global__ __launch_bounds__(256) void bcat(const float* __restrict__ a,
    const float* __restrict__ b, float* __restrict__ o)
{
  int i = blockIdx.x*256 + threadIdx.x;
  o[i] = (i < 1024) ? a[i] : b[i-1024];
}

// ================= 256x256 8-phase GEMM (T2+T3+T4+T5) ========================
// C[M][N] = A[M][K]bf16 @ Wt[N][K]^T + bias. 512 thr = 8 waves (2Mx4N).
// LDS 128KB: 2 bufs x {A 256x64 (32K), B 256x64 (32K)}, 128B rows, XOR swizzle.
// Per K-tile: 4 phases; 2 chunk-stages/phase; one counted vmcnt(4)/tile.
// INVARIANT (m201): vmcnt(N) -> s_barrier -> first ds_read of newly-staged data.
template<int MH, int KS>
DEV void phase_mfma(f32x4 (&acc)[8][4], const bf16x8 (&aF)[4], const bf16x8 (&bB)[2][4]){
  __builtin_amdgcn_s_barrier();
  __builtin_amdgcn_s_setprio(1);
  #pragma unroll
  for (int i=0;i<4;i++)
    #pragma unroll
    for (int j=0;j<4;j++)
      acc[MH*4+i][j] = __builtin_amdgcn_mfma_f32_16x16x32_bf16(aF[i], bB[KS][j], acc[MH*4+i][j], 0,0,0);
  __builtin_amdgcn_s_setprio(0);
  __builtin_amdgcn_s_barrier();
}

template<int EPI>
__global__ __launch_bounds__(512,2) void gemm256(
  const unsigned char* __restrict__ A, const unsigned char* __restrict__ Wt,
  const float* __restrict__ bias, void* __restrict__ Cout,
  const float* __restrict__ Xadd, int M, int N, int K, int gxshift)
{
  __shared__ __align__(16) unsigned char lds[131072];
  const int nwg = gridDim.x;
  const int chunk = nwg >> 3;
  const int wg = blockIdx.x;
  const int lg = (wg & 7) * chunk + (wg >> 3);
  const int bx = lg & ((1<<gxshift)-1);
  const int by = lg >> gxshift;
  const int tid = threadIdx.x, w = tid>>6, lane = tid&63;
  const int l15 = lane&15, lq = lane>>4;
  const int wr = w>>2, wc = w&3;
  const int m0 = by<<8, n0 = bx<<8;
  const size_t K2 = (size_t)K<<1;
  const int NT = K>>6;

  // staging geometry: chunk = 64 rows x 128B = 8KB = 1 load/thread
  const int srow = w*8 + (lane>>3);                 // row within chunk
  const int scs  = (((lane&7) ^ (lane>>3))<<4);     // pre-swizzled 16B col

  f32x4 acc[8][4];
  f32x4 zero = {0.f,0.f,0.f,0.f};
  #pragma unroll
  for (int i=0;i<8;i++)
    #pragma unroll
    for (int j=0;j<4;j++) acc[i][j] = zero;

  // stage chunk c (0..3) of matrix mat (0=A,1=B) for K-tile t into buffer bf
  auto stg = [&](int bf, int mat, int c, int t){
    const unsigned char* src = mat ? Wt : A;
    int prow = mat ? n0 : m0;
    gl_lds16(src + (size_t)(prow + c*64 + srow)*K2 + ((size_t)t<<7) + scs,
             lds + bf*65536 + mat*32768 + c*8192 + w*1024);
  };
  auto ldA = [&](int mh, int i, int ks, int bf)->bf16x8 {
    int r = wr*128 + mh*64 + i*16 + l15;
    return *(const bf16x8*)(lds + bf*65536 + r*128 + ((ks*64 + lq*16) ^ ((r&7)<<4)));
  };
  auto ldB = [&](int j, int ks, int bf)->bf16x8 {
    int r = wc*64 + j*16 + l15;
    return *(const bf16x8*)(lds + bf*65536 + 32768 + r*128 + ((ks*64 + lq*16) ^ ((r&7)<<4)));
  };

  // prologue: t0 fully (a0a2,b0..b3,a1a3) + t1 (a0a2,b0b1)  [12 loads]
  stg(0,0,0,0); stg(0,0,2,0);
  stg(0,1,0,0); stg(0,1,1,0);
  stg(0,1,2,0); stg(0,1,3,0);
  stg(0,0,1,0); stg(0,0,3,0);
  stg(1,0,0,1); stg(1,0,2,1);
  stg(1,1,0,1); stg(1,1,1,1);

  for (int u=0; u<NT; ++u){
    const int buf = u&1, nb = buf^1;
    if (u+1 < NT) { asm volatile("s_waitcnt vmcnt(4)" ::: "memory"); }
    else          { asm volatile("s_waitcnt vmcnt(0)" ::: "memory"); }
    __builtin_amdgcn_sched_barrier(0);
    // cross-wave visibility: my vmcnt only proves MY loads landed; barrier
    // makes everyone's tile-u staging visible before any ds_read of it.
    __builtin_amdgcn_s_barrier();

    bf16x8 bB[2][4];
    bf16x8 aF[4];
    // P0: (mh0, ks0) ; stage (u+1).b2b3 -> other buffer
    #pragma unroll
    for (int j=0;j<4;j++) bB[0][j] = ldB(j,0,buf);
    #pragma unroll
    for (int i=0;i<4;i++) aF[i] = ldA(0,i,0,buf);
    if (u+1 < NT){ stg(nb,1,2,u+1); stg(nb,1,3,u+1); }
    phase_mfma<0,0>(acc, aF, bB);
    // P1: (mh0, ks1) ; stage (u+1).a1a3
    #pragma unroll
    for (int j=0;j<4;j++) bB[1][j] = ldB(j,1,buf);
    #pragma unroll
    for (int i=0;i<4;i++) aF[i] = ldA(0,i,1,buf);
    if (u+1 < NT){ stg(nb,0,1,u+1); stg(nb,0,3,u+1); }
    phase_mfma<0,1>(acc, aF, bB);
    // P2: (mh1, ks0) ; stage (u+2).a0a2 -> same buffer (a0,a2 fully read in P0/P1)
    #pragma unroll
    for (int i=0;i<4;i++) aF[i] = ldA(1,i,0,buf);
    if (u+2 < NT){ stg(buf,0,0,u+2); stg(buf,0,2,u+2); }
    phase_mfma<1,0>(acc, aF, bB);
    // P3: (mh1, ks1) ; stage (u+2).b0b1 (b fully read in P0/P1)
    #pragma unroll
    for (int i=0;i<4;i++) aF[i] = ldA(1,i,1,buf);
    if (u+2 < NT){ stg(buf,1,0,u+2); stg(buf,1,1,u+2); }
    phase_mfma<1,1>(acc, aF, bB);
  }

  #pragma unroll
  for (int j=0;j<4;j++){
    int n = n0 + wc*64 + j*16 + l15;
    float bv = bias[n];
    #pragma unroll
    for (int mf=0;mf<8;mf++){
      int mb = m0 + wr*128 + mf*16 + lq*4;
      #pragma unroll
      for (int r=0;r<4;r++){
        size_t idx = (size_t)(mb+r)*N + n;
        float val = acc[mf][j][r] + bv;
        if (EPI==0) ((unsigned short*)Cout)[idx] = f2bf(val);
        else        ((float*)Cout)[idx] = Xadd[idx] + val;
      }
    }
  }
}

// ---------------- V transpose into pre-swizzled V^T global layout --------------
__global__ __launch_bounds__(256) void vtransp(const unsigned short* __restrict__ v,
                                               int vstride, unsigned char* __restrict__ vt)
{
  __shared__ __align__(16) unsigned short tile[16384]; // [n=256][d=64]
  int h = blockIdx.x, b = blockIdx.y, tid = threadIdx.x;
  const unsigned short* src = v + (size_t)b*256*vstride + h*64;
  #pragma unroll
  for (int it=0; it<8; ++it){
    int idx = it*256 + tid;
    int n = idx>>3, dc = idx&7;
    *(f32x4*)&tile[n*64 + dc*8] = *(const f32x4*)(src + (size_t)n*vstride + dc*8);
  }
  __syncthreads();
  unsigned char* dst = vt + (size_t)(b*16+h)*32768;
  #pragma unroll
  for (int it=0; it<8; ++it){
    int idx = it*256 + tid;
    int d = idx>>5, nc = idx&31;
    u16x8 o;
    #pragma unroll
    for (int j=0;j<8;j++) o[j] = tile[(nc*8+j)*64 + d];
    *(u16x8*)(dst + d*512 + ((nc*16) ^ ((d&7)<<4))) = o;
  }
}

// ---------------- fused cross-attention, one block per (b,h,t-tile of 64) -----
__global__ __launch_bounds__(256,2) void attn64(
  const unsigned char* __restrict__ qg, const unsigned char* __restrict__ kg,
  int kstride, const unsigned char* __restrict__ vtg, const int* __restrict__ cond,
  unsigned short* __restrict__ yout)
{
  __shared__ __align__(16) unsigned char lds[73728]; // [0,32K): K/P ; [32K,64K): V^T ; [64K,72K): Q
  const int wg = blockIdx.x;
  const int lg = (wg & 7) * 1024 + (wg >> 3);       // 8192 blocks, chunk=1024
  const int t0 = (lg & 15) * 64;
  const int h  = (lg >> 4) & 15;
  const int b  = lg >> 8;
  const int tid = threadIdx.x, w = tid>>6, lane = tid&63;
  const int l15 = lane&15, lq = lane>>4;

  const unsigned char* kbase = kg + (size_t)b*256*kstride + (size_t)h*128;
  const unsigned char* vtb   = vtg + (size_t)(b*16+h)*32768;
  #pragma unroll
  for (int i=0;i<8;i++){
    int base = (w*8+i)*1024;
    int n  = (base>>7) + (lane>>3);
    int cb = (lane&7)<<4;
    gl_lds16(kbase + (size_t)n*kstride + (cb ^ ((n&7)<<4)), lds + base);
    gl_lds16(vtb + base + lane*16, lds + 32768 + base);
  }
  const unsigned char* qbase = qg + (size_t)(b*1024 + t0)*2048 + h*128;
  #pragma unroll
  for (int i=0;i<2;i++){
    int row = i*32 + (tid>>3);
    int cs  = ((tid&7)<<4) ^ ((row&7)<<4);
    gl_lds16(qbase + (size_t)row*2048 + cs, lds + 65536 + i*4096 + w*1024);
  }
  __syncthreads();

  const int qr = w*16 + l15;
  const int qsw = (qr&7)<<4;
  bf16x8 aq0 = *(const bf16x8*)(lds + 65536 + qr*128 + ((lq*16) ^ qsw));
  bf16x8 aq1 = *(const bf16x8*)(lds + 65536 + qr*128 + ((64 + lq*16) ^ qsw));

  f32x4 zero = {0.f,0.f,0.f,0.f};
  f32x4 s[16];
  #pragma unroll
  for (int nt=0;nt<16;nt++) s[nt] = zero;
  #pragma unroll
  for (int nt=0;nt<16;nt++){
    int n = nt*16 + l15;
    int rb = n<<7, sw = (n&7)<<4;
    bf16x8 kb0 = *(const bf16x8*)(lds + rb + ((lq*16) ^ sw));
    bf16x8 kb1 = *(const bf16x8*)(lds + rb + ((64 + lq*16) ^ sw));
    s[nt] = __builtin_amdgcn_mfma_f32_16x16x32_bf16(aq0, kb0, s[nt], 0,0,0);
    s[nt] = __builtin_amdgcn_mfma_f32_16x16x32_bf16(aq1, kb1, s[nt], 0,0,0);
  }
  #pragma unroll
  for (int r=0;r<4;r++){
    float m = s[0][r];
    #pragma unroll
    for (int nt=1;nt<16;nt++) m = fmaxf(m, s[nt][r]);
    m = fmaxf(m, __shfl_xor(m,1,64));
    m = fmaxf(m, __shfl_xor(m,2,64));
    m = fmaxf(m, __shfl_xor(m,4,64));
    m = fmaxf(m, __shfl_xor(m,8,64));
    float sum = 0.f;
    #pragma unroll
    for (int nt=0;nt<16;nt++){ float p = __expf(s[nt][r]-m); s[nt][r]=p; sum+=p; }
    sum += __shfl_xor(sum,1,64);
    sum += __shfl_xor(sum,2,64);
    sum += __shfl_xor(sum,4,64);
    sum += __shfl_xor(sum,8,64);
    float inv = 1.f/sum;
    #pragma unroll
    for (int nt=0;nt<16;nt++) s[nt][r] *= inv;
  }
  __syncthreads();
  #pragma unroll
  for (int nt=0;nt<16;nt++){
    int n = nt*16 + l15;
    int nb = (n>>3)<<4, nr = (n&7)<<1;
    #pragma unroll
    for (int r=0;r<4;r++){
      int tl = w*16 + lq*4 + r;
      *(unsigned short*)(lds + tl*512 + ((nb ^ ((tl&7)<<4)) | nr)) = f2bf(s[nt][r]);
    }
  }
  __syncthreads();
  f32x4 yv[4];
  #pragma unroll
  for (int dt=0;dt<4;dt++) yv[dt] = zero;
  const int tl = w*16 + l15;
  const int swp = (tl&7)<<4;
  #pragma unroll
  for (int kc=0;kc<8;kc++){
    bf16x8 pa = *(const bf16x8*)(lds + tl*512 + ((kc*64 + lq*16) ^ swp));
    #pragma unroll
    for (int dt=0;dt<4;dt++){
      int d = dt*16 + l15;
      bf16x8 vbv = *(const bf16x8*)(lds + 32768 + d*512 + ((kc*64 + lq*16) ^ ((d&7)<<4)));
      yv[dt] = __builtin_amdgcn_mfma_f32_16x16x32_bf16(pa, vbv, yv[dt], 0,0,0);
    }
  }
  float tc = (cond[b] % 10 > 0) ? 1.f : 0.f;
  #pragma unroll
  for (int dt=0;dt<4;dt++){
    #pragma unroll
    for (int r=0;r<4;r++){
      int tt = t0 + w*16 + lq*4 + r;
      yout[(size_t)(b*1024 + tt)*1024 + h*64 + dt*16 + l15] = f2bf(yv[dt][r]*tc);
    }
  }
}

// ---------------- emb GEMM: silu(emb)[32][2048] @ We[2048][2048] (k-split) -----
__global__ __launch_bounds__(256) void embgemm(const float* __restrict__ emb,
    const float* __restrict__ We, float* __restrict__ epart)
{
  __shared__ float a[32][128];
  int cb = blockIdx.x, ks = blockIdx.y, tid = threadIdx.x;
  int k0 = ks<<7;
  #pragma unroll
  for (int it=0; it<4; ++it){
    int fi = it*256 + tid;
    int r = fi>>5, c4 = (fi&31)<<2;
    float4 vv = *(const float4*)(emb + (size_t)r*2048 + k0 + c4);
    vv.x = silu_f(vv.x); vv.y = silu_f(vv.y); vv.z = silu_f(vv.z); vv.w = silu_f(vv.w);
    *(float4*)&a[r][c4] = vv;
  }
  __syncthreads();
  int c0 = (cb<<8) + tid;
  float acc[32];
  #pragma unroll
  for (int r=0;r<32;r++) acc[r]=0.f;
  for (int kk=0;kk<128;kk++){
    float wv = We[(size_t)(k0+kk)*2048 + c0];
    #pragma unroll
    for (int r=0;r<32;r++) acc[r] += a[r][kk]*wv;
  }
  #pragma unroll
  for (int r=0;r<32;r++) epart[(size_t)(ks*32 + r)*2048 + c0] = acc[r];
}

__global__ __launch_bounds__(256) void embred(const float* __restrict__ epart,
    const float* __restrict__ be, float* __restrict__ eo)
{
  int idx = blockIdx.x*256 + threadIdx.x;   // 65536 = 32*2048
  float s = be[idx & 2047];
  #pragma unroll
  for (int ks=0;ks<16;ks++) s += epart[(size_t)ks*65536 + idx];
  eo[idx] = s;
}

// ---------------- stylization: LN(y)*(1+scale)+shift -> silu -> bf16 ----------
__global__ __launch_bounds__(256) void styl(const unsigned short* __restrict__ y,
    const float* __restrict__ g, const float* __restrict__ bt,
    const float* __restrict__ eo, unsigned short* __restrict__ hout)
{
  int row = blockIdx.x, t = threadIdx.x, b = row>>10;
  ushort4 yv4 = ((const ushort4*)(y + (size_t)row*1024))[t];
  float in[4] = {bf2f(yv4.x), bf2f(yv4.y), bf2f(yv4.z), bf2f(yv4.w)};
  float s  = in[0]+in[1]+in[2]+in[3];
  float s2 = in[0]*in[0]+in[1]*in[1]+in[2]*in[2]+in[3]*in[3];
  #pragma unroll
  for (int o=32;o;o>>=1){ s += __shfl_down(s,o,64); s2 += __shfl_down(s2,o,64); }
  __shared__ float red[8];
  if ((t&63)==0){ red[t>>6]=s; red[4+(t>>6)]=s2; }
  __syncthreads();
  float fs  = red[0]+red[1]+red[2]+red[3];
  float fs2 = red[4]+red[5]+red[6]+red[7];
  float mean = fs*(1.f/1024.f);
  float var  = fmaxf(fs2*(1.f/1024.f) - mean*mean, 0.f);
  float rstd = rsqrtf(var + 1e-5f);
  float4 gv = ((const float4*)g)[t];
  float4 bv = ((const float4*)bt)[t];
  float4 sc = ((const float4*)(eo + (size_t)b*2048))[t];
  float4 sh = ((const float4*)(eo + (size_t)b*2048 + 1024))[t];
  float gg[4]  = {gv.x,gv.y,gv.z,gv.w};
  float bb[4]  = {bv.x,bv.y,bv.z,bv.w};
  float scs[4] = {sc.x,sc.y,sc.z,sc.w};
  float shs[4] = {sh.x,sh.y,sh.z,sh.w};
  unsigned short oo[4];
  #pragma unroll
  for (int c=0;c<4;c++){
    float hv = (in[c]-mean)*rstd*gg[c] + bb[c];
    hv = hv*(1.f+scs[c]) + shs[c];
    oo[c] = f2bf(silu_f(hv));
  }
  ushort4 o4; o4.x=oo[0]; o4.y=oo[1]; o4.z=oo[2]; o4.w=oo[3];
  *(ushort4*)(hout + (size_t)row*1024 + t*4) = o4;
}

// ---------------- launcher ----------------------------------------------------
extern "C" void kernel_launch(void* const* d_in, const int* in_sizes, int n_in,
                              void* d_out, int out_size, void* d_ws, size_t ws_size,
                              hipStream_t stream) {
  const float* x      = (const float*)d_in[0];
  const float* xf     = (const float*)d_in[1];
  const float* emb    = (const float*)d_in[2];
  const int*   cond   = (const int*)d_in[4];
  const float* ln_x_g = (const float*)d_in[5];
  const float* ln_x_b = (const float*)d_in[6];
  const float* ln_t_g = (const float*)d_in[7];
  const float* ln_t_b = (const float*)d_in[8];
  const float* Wq     = (const float*)d_in[9];
  const float* bq     = (const float*)d_in[10];
  const float* Wk     = (const float*)d_in[11];
  const float* bk     = (const float*)d_in[12];
  const float* Wv     = (const float*)d_in[13];
  const float* bv     = (const float*)d_in[14];
  const float* We     = (const float*)d_in[15];
  const float* be     = (const float*)d_in[16];
  const float* ln_y_g = (const float*)d_in[17];
  const float* ln_y_b = (const float*)d_in[18];
  const float* Wo     = (const float*)d_in[19];
  const float* bo     = (const float*)d_in[20];
  float* out = (float*)d_out;

  unsigned char* ws = (unsigned char*)d_ws;
  size_t off = 0;
  auto take = [&](size_t n){ unsigned char* p = ws + off; off += (n + 255) & ~(size_t)255; return p; };
  unsigned char* r1   = take(67108864);   // xln bf16 -> (epart) -> h bf16
  unsigned char* qb   = take(67108864);   // q bf16 -> y bf16 (in place)
  unsigned char* xfn  = take(12582912);   // LN(xf) bf16
  unsigned char* kvb  = take(33554432);   // fused k|v bf16 [8192][2048]
  unsigned char* vtb  = take(16777216);   // v^T pre-swizzled bf16
  unsigned char* wqt  = take(2097152);
  unsigned char* wkvt = take(3145728);    // [2048][768] bf16
  unsigned char* wot  = take(2097152);
  unsigned char* eo   = take(262144);     // emb_out fp32 [32][2048]
  unsigned char* bkv  = take(8192);       // concat bias fp32 [2048]
  float* epart = (float*)r1;              // [16][32][2048] fp32, aliases r1

  dim3 blk(256);
  dim3 blk512(512);
  // weights -> bf16 transposed
  wconv<<<dim3(32,32), blk, 0, stream>>>(Wq, (unsigned short*)wqt, 1024, 1024);
  wconv<<<dim3(32,24), blk, 0, stream>>>(Wk, (unsigned short*)wkvt,  768, 1024);
  wconv<<<dim3(32,24), blk, 0, stream>>>(Wv, (unsigned short*)wkvt + (size_t)1024*768, 768, 1024);
  wconv<<<dim3(32,32), blk, 0, stream>>>(Wo, (unsigned short*)wot, 1024, 1024);
  bcat<<<8, blk, 0, stream>>>(bk, bv, (float*)bkv);
  // layernorms
  ln_rows<<<32768, blk, 0, stream>>>(x,  ln_x_g, ln_x_b, (unsigned short*)r1,  1024, 256);
  ln_rows<<<8192,  blk, 0, stream>>>(xf, ln_t_g, ln_t_b, (unsigned short*)xfn,  768, 192);
  // projections: 256^2 8-phase GEMM, XCD-chunked swizzle
  gemm256<0><<<512, blk512, 0, stream>>>(r1,  wqt,  bq, qb, nullptr, 32768, 1024, 1024, 2);
  gemm256<0><<<256, blk512, 0, stream>>>(xfn, wkvt, (const float*)bkv, kvb, nullptr, 8192, 2048, 768, 3);
  // v (cols 1024..2047 of kvb) -> swizzled v^T
  vtransp<<<dim3(16,32), blk, 0, stream>>>((const unsigned short*)kvb + 1024, 2048, vtb);
  // emb path (epart aliases r1; runs after the q-GEMM consumed xln)
  embgemm<<<dim3(8,16), blk, 0, stream>>>(emb, We, epart);
  embred<<<256, blk, 0, stream>>>(epart, be, (float*)eo);
  // attention: y bf16 written in place over q
  attn64<<<8192, blk, 0, stream>>>(qb, kvb, 4096, vtb, cond, (unsigned short*)qb);
  // stylization -> h bf16 (overwrites r1)
  styl<<<32768, blk, 0, stream>>>((const unsigned short*)qb, ln_y_g, ln_y_b, (const float*)eo, (unsigned short*)r1);
  // output projection + residual -> d_out
  gemm256<1><<<512, blk512, 0, stream>>>(r1, wot, bo, out, x, 32768, 1024, 1024, 2);
}

// Round 6
// 469.585 us; speedup vs baseline: 1.0559x; 1.0559x over previous
//
#include <hip/hip_runtime.h>
#include <hip/hip_bf16.h>

#define DEV __device__ __forceinline__

typedef __attribute__((ext_vector_type(8))) short bf16x8;
typedef __attribute__((ext_vector_type(4))) float f32x4;
typedef __attribute__((ext_vector_type(8))) unsigned short u16x8;

DEV unsigned short f2bf(float f){
  unsigned int b = __float_as_uint(f);
  return (unsigned short)((b + 0x7fffu + ((b >> 16) & 1u)) >> 16);
}
DEV float bf2f(unsigned short u){ return __uint_as_float(((unsigned int)u)<<16); }

DEV float silu_f(float v){ return v / (1.f + __expf(-v)); }

DEV void gl_lds16(const void* g, void* l){
  __builtin_amdgcn_global_load_lds((const __attribute__((address_space(1))) void*)g,
                                   (__attribute__((address_space(3))) void*)l, 16, 0, 0);
}
DEV void wait_lds(){
  asm volatile("s_waitcnt lgkmcnt(0)" ::: "memory");
  __builtin_amdgcn_sched_barrier(0);
}

// ---------------- merged LayerNorm (x rows then xf rows) ----------------
__global__ __launch_bounds__(256) void ln_all(const float* __restrict__ x,
    const float* __restrict__ xf,
    const float* __restrict__ gx, const float* __restrict__ bx_,
    const float* __restrict__ gt, const float* __restrict__ bt,
    unsigned short* __restrict__ ox, unsigned short* __restrict__ ot)
{
  int row = blockIdx.x, t = threadIdx.x;
  const float* src; const float* g; const float* bb; unsigned short* out;
  int D, nvec;
  if (row < 32768){ src = x + (size_t)row*1024; g = gx; bb = bx_; out = ox + (size_t)row*1024; D = 1024; nvec = 256; }
  else { int r2 = row - 32768; src = xf + (size_t)r2*768; g = gt; bb = bt; out = ot + (size_t)r2*768; D = 768; nvec = 192; }
  float4 v = make_float4(0.f,0.f,0.f,0.f);
  if (t < nvec) v = ((const float4*)src)[t];
  float s  = v.x+v.y+v.z+v.w;
  float s2 = v.x*v.x+v.y*v.y+v.z*v.z+v.w*v.w;
  #pragma unroll
  for (int o=32;o;o>>=1){ s += __shfl_down(s,o,64); s2 += __shfl_down(s2,o,64); }
  __shared__ float red[8];
  if ((t&63)==0){ red[t>>6]=s; red[4+(t>>6)]=s2; }
  __syncthreads();
  float fs  = red[0]+red[1]+red[2]+red[3];
  float fs2 = red[4]+red[5]+red[6]+red[7];
  float mean = fs / (float)D;
  float var  = fmaxf(fs2/(float)D - mean*mean, 0.f);
  float rstd = rsqrtf(var + 1e-5f);
  if (t < nvec){
    float4 gv = ((const float4*)g)[t];
    float4 bv = ((const float4*)bb)[t];
    ushort4 o4;
    o4.x = f2bf((v.x-mean)*rstd*gv.x + bv.x);
    o4.y = f2bf((v.y-mean)*rstd*gv.y + bv.y);
    o4.z = f2bf((v.z-mean)*rstd*gv.z + bv.z);
    o4.w = f2bf((v.w-mean)*rstd*gv.w + bv.w);
    *(ushort4*)(out + t*4) = o4;
  }
}

// ---------------- prep: all weight converts + bias concat in one kernel --------
DEV void wtile(const float* W, unsigned short* Wt, int K, int N, int nt, int kt, int tid,
               float (*tile)[33])
{
  int n0 = nt<<5, k0 = kt<<5;
  int tx = tid & 31, ty = tid >> 5;
  #pragma unroll
  for (int i=0;i<4;i++)
    tile[ty + i*8][tx] = W[(size_t)(k0 + ty + i*8)*N + n0 + tx];
  __syncthreads();
  #pragma unroll
  for (int i=0;i<4;i++)
    Wt[(size_t)(n0 + ty + i*8)*K + k0 + tx] = f2bf(tile[tx][ty + i*8]);
}

__global__ __launch_bounds__(256) void prep(
    const float* __restrict__ Wq, const float* __restrict__ Wk,
    const float* __restrict__ Wv, const float* __restrict__ Wo,
    const float* __restrict__ bk, const float* __restrict__ bv,
    unsigned short* __restrict__ wqt, unsigned short* __restrict__ wkvt,
    unsigned short* __restrict__ wot, float* __restrict__ bkv)
{
  __shared__ float tile[32][33];
  int id = blockIdx.x, tid = threadIdx.x;
  if (id < 8){
    int i = id*256 + tid;
    bkv[i] = (i < 1024) ? bk[i] : bv[i-1024];
    return;
  }
  id -= 8;
  if (id < 1024){ wtile(Wq, wqt, 1024, 1024, id & 31, id >> 5, tid, tile); return; }
  id -= 1024;
  if (id < 768){ wtile(Wk, wkvt, 768, 1024, id & 31, id >> 5, tid, tile); return; }
  id -= 768;
  if (id < 768){ wtile(Wv, wkvt + (size_t)1024*768, 768, 1024, id & 31, id >> 5, tid, tile); return; }
  id -= 768;
  wtile(Wo, wot, 1024, 1024, id & 31, id >> 5, tid, tile);
}

// ================= 256x256 8-phase GEMM (T1+T2+T3+T4+T5) =====================
// C[M][N] = A[M][K]bf16 @ Wt[N][K]^T + bias. 512 thr = 8 waves (2Mx4N).
// LDS 128KB: 2 bufs x {A 256x64 (32K), B 256x64 (32K)}, 128B rows, XOR swizzle.
// 4 phases/K-tile, 2 barriers/phase; counted vmcnt once per tile inside P3.
// INVARIANT: vmcnt(N) precedes a barrier that precedes the first ds_read of
// newly staged data (cross-wave visibility).
// EPI: 0 = bf16 C. 1 = fp32 C = Xadd + val. 2 = KV: K-half bf16 [M][1024],
//      V-half scattered into pre-swizzled vt blocks.
template<int MH>
DEV void do_mfma(f32x4 (&acc)[8][4], const bf16x8 (&aF)[4], const bf16x8 (&bk)[4]){
  __builtin_amdgcn_s_setprio(1);
  #pragma unroll
  for (int i=0;i<4;i++)
    #pragma unroll
    for (int j=0;j<4;j++)
      acc[MH*4+i][j] = __builtin_amdgcn_mfma_f32_16x16x32_bf16(aF[i], bk[j], acc[MH*4+i][j], 0,0,0);
  __builtin_amdgcn_s_setprio(0);
}

template<int EPI>
__global__ __launch_bounds__(512,2) void gemm256(
  const unsigned char* __restrict__ A, const unsigned char* __restrict__ Wt,
  const float* __restrict__ bias, void* __restrict__ Cout,
  const float* __restrict__ Xadd, unsigned char* __restrict__ vt,
  int M, int N, int K, int gxshift)
{
  __shared__ __align__(16) unsigned char lds[131072];
  const int nwg = gridDim.x;
  const int chunk = nwg >> 3;
  const int wg = blockIdx.x;
  const int lg = (wg & 7) * chunk + (wg >> 3);
  const int bx = lg & ((1<<gxshift)-1);
  const int by = lg >> gxshift;
  const int tid = threadIdx.x, w = tid>>6, lane = tid&63;
  const int l15 = lane&15, lq = lane>>4;
  const int wr = w>>2, wc = w&3;
  const int m0 = by<<8, n0 = bx<<8;
  const size_t K2 = (size_t)K<<1;
  const int NT = K>>6;

  const int srow = w*8 + (lane>>3);
  const int scs  = (((lane&7) ^ (lane>>3))<<4);

  f32x4 acc[8][4];
  f32x4 zero = {0.f,0.f,0.f,0.f};
  #pragma unroll
  for (int i=0;i<8;i++)
    #pragma unroll
    for (int j=0;j<4;j++) acc[i][j] = zero;

  auto stg = [&](int bf, int mat, int c, int t){
    const unsigned char* src = mat ? Wt : A;
    int prow = mat ? n0 : m0;
    gl_lds16(src + (size_t)(prow + c*64 + srow)*K2 + ((size_t)t<<7) + scs,
             lds + bf*65536 + mat*32768 + c*8192 + w*1024);
  };
  auto ldA = [&](int mh, int i, int ks, int bf)->bf16x8 {
    int r = wr*128 + mh*64 + i*16 + l15;
    return *(const bf16x8*)(lds + bf*65536 + r*128 + ((ks*64 + lq*16) ^ ((r&7)<<4)));
  };
  auto ldB = [&](int j, int ks, int bf)->bf16x8 {
    int r = wc*64 + j*16 + l15;
    return *(const bf16x8*)(lds + bf*65536 + 32768 + r*128 + ((ks*64 + lq*16) ^ ((r&7)<<4)));
  };

  // prologue: t0 fully + t1 half  [12 loads]
  stg(0,0,0,0); stg(0,0,2,0);
  stg(0,1,0,0); stg(0,1,1,0);
  stg(0,1,2,0); stg(0,1,3,0);
  stg(0,0,1,0); stg(0,0,3,0);
  stg(1,0,0,1); stg(1,0,2,1);
  stg(1,1,0,1); stg(1,1,1,1);
  asm volatile("s_waitcnt vmcnt(4)" ::: "memory");
  __builtin_amdgcn_s_barrier();

  for (int u=0; u<NT; ++u){
    const int buf = u&1, nb = buf^1;
    bf16x8 aF[4], bB0[4], bB1[4];
    // ---- P0: (mh0, ks0); stage (u+1).b2b3
    #pragma unroll
    for (int j=0;j<4;j++) bB0[j] = ldB(j,0,buf);
    #pragma unroll
    for (int i=0;i<4;i++) aF[i] = ldA(0,i,0,buf);
    if (u+1 < NT){ stg(nb,1,2,u+1); stg(nb,1,3,u+1); }
    __builtin_amdgcn_s_barrier();
    wait_lds();
    do_mfma<0>(acc, aF, bB0);
    __builtin_amdgcn_s_barrier();
    // ---- P1: (mh0, ks1); stage (u+1).a1a3
    #pragma unroll
    for (int j=0;j<4;j++) bB1[j] = ldB(j,1,buf);
    #pragma unroll
    for (int i=0;i<4;i++) aF[i] = ldA(0,i,1,buf);
    if (u+1 < NT){ stg(nb,0,1,u+1); stg(nb,0,3,u+1); }
    __builtin_amdgcn_s_barrier();
    wait_lds();
    do_mfma<0>(acc, aF, bB1);
    __builtin_amdgcn_s_barrier();
    // ---- P2: (mh1, ks0); stage (u+2).a0a2 (chunks dead since P1-end barrier)
    #pragma unroll
    for (int i=0;i<4;i++) aF[i] = ldA(1,i,0,buf);
    if (u+2 < NT){ stg(buf,0,0,u+2); stg(buf,0,2,u+2); }
    __builtin_amdgcn_s_barrier();
    wait_lds();
    do_mfma<1>(acc, aF, bB0);
    __builtin_amdgcn_s_barrier();
    // ---- P3: (mh1, ks1); stage (u+2).b0b1; counted vmcnt before end barrier
    #pragma unroll
    for (int i=0;i<4;i++) aF[i] = ldA(1,i,1,buf);
    if (u+2 < NT){ stg(buf,1,0,u+2); stg(buf,1,1,u+2); }
    __builtin_amdgcn_s_barrier();
    wait_lds();
    do_mfma<1>(acc, aF, bB1);
    if (u+1 < NT){
      if (u+2 < NT) { asm volatile("s_waitcnt vmcnt(4)" ::: "memory"); }
      else          { asm volatile("s_waitcnt vmcnt(0)" ::: "memory"); }
      __builtin_amdgcn_sched_barrier(0);
    }
    __builtin_amdgcn_s_barrier();   // visibility for next iteration's P0 reads
  }

  #pragma unroll
  for (int j=0;j<4;j++){
    int n = n0 + wc*64 + j*16 + l15;
    float bvs = bias[n];
    #pragma unroll
    for (int mf=0;mf<8;mf++){
      int mb = m0 + wr*128 + mf*16 + lq*4;
      #pragma unroll
      for (int r=0;r<4;r++){
        int m = mb + r;
        float val = acc[mf][j][r] + bvs;
        if (EPI==0){
          ((unsigned short*)Cout)[(size_t)m*N + n] = f2bf(val);
        } else if (EPI==1){
          size_t idx = (size_t)m*N + n;
          ((float*)Cout)[idx] = Xadd[idx] + val;
        } else {
          if (n0 < 1024){
            ((unsigned short*)Cout)[(size_t)m*1024 + n] = f2bf(val);
          } else {
            int d = n - 1024 - ((n0-1024)&~63) - 0; d = (n-1024)&63;
            int hh = (n-1024)>>6;
            int bb_ = m>>8, nk = m&255;
            vt[((size_t)(bb_*16+hh)<<15) + d*512 + (((nk>>3)<<4) ^ ((d&7)<<4)) + ((nk&7)<<1)] = f2bf(val) & 0xff ? 0 : 0; // placeholder avoided below
            *(unsigned short*)(vt + ((size_t)(bb_*16+hh)<<15) + d*512
                + (((nk>>3)<<4) ^ ((d&7)<<4)) + ((nk&7)<<1)) = f2bf(val);
          }
        }
      }
    }
  }
}

// ---------------- fused cross-attention, one block per (b,h,t-tile of 64) -----
__global__ __launch_bounds__(256,2) void attn64(
  const unsigned char* __restrict__ qg, const unsigned char* __restrict__ kg,
  int kstride, const unsigned char* __restrict__ vtg, const int* __restrict__ cond,
  unsigned short* __restrict__ yout)
{
  __shared__ __align__(16) unsigned char lds[73728];
  const int wg = blockIdx.x;
  const int lg = (wg & 7) * 1024 + (wg >> 3);
  const int t0 = (lg & 15) * 64;
  const int h  = (lg >> 4) & 15;
  const int b  = lg >> 8;
  const int tid = threadIdx.x, w = tid>>6, lane = tid&63;
  const int l15 = lane&15, lq = lane>>4;

  const unsigned char* kbase = kg + (size_t)b*256*kstride + (size_t)h*128;
  const unsigned char* vtb   = vtg + (size_t)(b*16+h)*32768;
  #pragma unroll
  for (int i=0;i<8;i++){
    int base = (w*8+i)*1024;
    int n  = (base>>7) + (lane>>3);
    int cb = (lane&7)<<4;
    gl_lds16(kbase + (size_t)n*kstride + (cb ^ ((n&7)<<4)), lds + base);
    gl_lds16(vtb + base + lane*16, lds + 32768 + base);
  }
  const unsigned char* qbase = qg + (size_t)(b*1024 + t0)*2048 + h*128;
  #pragma unroll
  for (int i=0;i<2;i++){
    int row = i*32 + (tid>>3);
    int cs  = ((tid&7)<<4) ^ ((row&7)<<4);
    gl_lds16(qbase + (size_t)row*2048 + cs, lds + 65536 + i*4096 + w*1024);
  }
  __syncthreads();

  const int qr = w*16 + l15;
  const int qsw = (qr&7)<<4;
  bf16x8 aq0 = *(const bf16x8*)(lds + 65536 + qr*128 + ((lq*16) ^ qsw));
  bf16x8 aq1 = *(const bf16x8*)(lds + 65536 + qr*128 + ((64 + lq*16) ^ qsw));

  f32x4 zero = {0.f,0.f,0.f,0.f};
  f32x4 s[16];
  #pragma unroll
  for (int nt=0;nt<16;nt++) s[nt] = zero;
  #pragma unroll
  for (int nt=0;nt<16;nt++){
    int n = nt*16 + l15;
    int rb = n<<7, sw = (n&7)<<4;
    bf16x8 kb0 = *(const bf16x8*)(lds + rb + ((lq*16) ^ sw));
    bf16x8 kb1 = *(const bf16x8*)(lds + rb + ((64 + lq*16) ^ sw));
    s[nt] = __builtin_amdgcn_mfma_f32_16x16x32_bf16(aq0, kb0, s[nt], 0,0,0);
    s[nt] = __builtin_amdgcn_mfma_f32_16x16x32_bf16(aq1, kb1, s[nt], 0,0,0);
  }
  #pragma unroll
  for (int r=0;r<4;r++){
    float m = s[0][r];
    #pragma unroll
    for (int nt=1;nt<16;nt++) m = fmaxf(m, s[nt][r]);
    m = fmaxf(m, __shfl_xor(m,1,64));
    m = fmaxf(m, __shfl_xor(m,2,64));
    m = fmaxf(m, __shfl_xor(m,4,64));
    m = fmaxf(m, __shfl_xor(m,8,64));
    float sum = 0.f;
    #pragma unroll
    for (int nt=0;nt<16;nt++){ float p = __expf(s[nt][r]-m); s[nt][r]=p; sum+=p; }
    sum += __shfl_xor(sum,1,64);
    sum += __shfl_xor(sum,2,64);
    sum += __shfl_xor(sum,4,64);
    sum += __shfl_xor(sum,8,64);
    float inv = 1.f/sum;
    #pragma unroll
    for (int nt=0;nt<16;nt++) s[nt][r] *= inv;
  }
  __syncthreads();
  #pragma unroll
  for (int nt=0;nt<16;nt++){
    int n = nt*16 + l15;
    int nb = (n>>3)<<4, nr = (n&7)<<1;
    #pragma unroll
    for (int r=0;r<4;r++){
      int tl = w*16 + lq*4 + r;
      *(unsigned short*)(lds + tl*512 + ((nb ^ ((tl&7)<<4)) | nr)) = f2bf(s[nt][r]);
    }
  }
  __syncthreads();
  f32x4 yv[4];
  #pragma unroll
  for (int dt=0;dt<4;dt++) yv[dt] = zero;
  const int tl = w*16 + l15;
  const int swp = (tl&7)<<4;
  #pragma unroll
  for (int kc=0;kc<8;kc++){
    bf16x8 pa = *(const bf16x8*)(lds + tl*512 + ((kc*64 + lq*16) ^ swp));
    #pragma unroll
    for (int dt=0;dt<4;dt++){
      int d = dt*16 + l15;
      bf16x8 vbv = *(const bf16x8*)(lds + 32768 + d*512 + ((kc*64 + lq*16) ^ ((d&7)<<4)));
      yv[dt] = __builtin_amdgcn_mfma_f32_16x16x32_bf16(pa, vbv, yv[dt], 0,0,0);
    }
  }
  float tc = (cond[b] % 10 > 0) ? 1.f : 0.f;
  #pragma unroll
  for (int dt=0;dt<4;dt++){
    #pragma unroll
    for (int r=0;r<4;r++){
      int tt = t0 + w*16 + lq*4 + r;
      yout[(size_t)(b*1024 + tt)*1024 + h*64 + dt*16 + l15] = f2bf(yv[dt][r]*tc);
    }
  }
}

// ---------------- emb GEMM + reduce -------------------------------------------
__global__ __launch_bounds__(256) void embgemm(const float* __restrict__ emb,
    const float* __restrict__ We, float* __restrict__ epart)
{
  __shared__ float a[32][128];
  int cb = blockIdx.x, ks = blockIdx.y, tid = threadIdx.x;
  int k0 = ks<<7;
  #pragma unroll
  for (int it=0; it<4; ++it){
    int fi = it*256 + tid;
    int r = fi>>5, c4 = (fi&31)<<2;
    float4 vv = *(const float4*)(emb + (size_t)r*2048 + k0 + c4);
    vv.x = silu_f(vv.x); vv.y = silu_f(vv.y); vv.z = silu_f(vv.z); vv.w = silu_f(vv.w);
    *(float4*)&a[r][c4] = vv;
  }
  __syncthreads();
  int c0 = (cb<<8) + tid;
  float acc[32];
  #pragma unroll
  for (int r=0;r<32;r++) acc[r]=0.f;
  for (int kk=0;kk<128;kk++){
    float wv = We[(size_t)(k0+kk)*2048 + c0];
    #pragma unroll
    for (int r=0;r<32;r++) acc[r] += a[r][kk]*wv;
  }
  #pragma unroll
  for (int r=0;r<32;r++) epart[(size_t)(ks*32 + r)*2048 + c0] = acc[r];
}

__global__ __launch_bounds__(256) void embred(const float* __restrict__ epart,
    const float* __restrict__ be, float* __restrict__ eo)
{
  int idx = blockIdx.x*256 + threadIdx.x;
  float s = be[idx & 2047];
  #pragma unroll
  for (int ks=0;ks<16;ks++) s += epart[(size_t)ks*65536 + idx];
  eo[idx] = s;
}

// ---------------- stylization --------------------------------------------------
__global__ __launch_bounds__(256) void styl(const unsigned short* __restrict__ y,
    const float* __restrict__ g, const float* __restrict__ bt,
    const float* __restrict__ eo, unsigned short* __restrict__ hout)
{
  int row = blockIdx.x, t = threadIdx.x, b = row>>10;
  ushort4 yv4 = ((const ushort4*)(y + (size_t)row*1024))[t];
  float in[4] = {bf2f(yv4.x), bf2f(yv4.y), bf2f(yv4.z), bf2f(yv4.w)};
  float s  = in[0]+in[1]+in[2]+in[3];
  float s2 = in[0]*in[0]+in[1]*in[1]+in[2]*in[2]+in[3]*in[3];
  #pragma unroll
  for (int o=32;o;o>>=1){ s += __shfl_down(s,o,64); s2 += __shfl_down(s2,o,64); }
  __shared__ float red[8];
  if ((t&63)==0){ red[t>>6]=s; red[4+(t>>6)]=s2; }
  __syncthreads();
  float fs  = red[0]+red[1]+red[2]+red[3];
  float fs2 = red[4]+red[5]+red[6]+red[7];
  float mean = fs*(1.f/1024.f);
  float var  = fmaxf(fs2*(1.f/1024.f) - mean*mean, 0.f);
  float rstd = rsqrtf(var + 1e-5f);
  float4 gv = ((const float4*)g)[t];
  float4 bv = ((const float4*)bt)[t];
  float4 sc = ((const float4*)(eo + (size_t)b*2048))[t];
  float4 sh = ((const float4*)(eo + (size_t)b*2048 + 1024))[t];
  float gg[4]  = {gv.x,gv.y,gv.z,gv.w};
  float bb[4]  = {bv.x,bv.y,bv.z,bv.w};
  float scs[4] = {sc.x,sc.y,sc.z,sc.w};
  float shs[4] = {sh.x,sh.y,sh.z,sh.w};
  unsigned short oo[4];
  #pragma unroll
  for (int c=0;c<4;c++){
    float hv = (in[c]-mean)*rstd*gg[c] + bb[c];
    hv = hv*(1.f+scs[c]) + shs[c];
    oo[c] = f2bf(silu_f(hv));
  }
  ushort4 o4; o4.x=oo[0]; o4.y=oo[1]; o4.z=oo[2]; o4.w=oo[3];
  *(ushort4*)(hout + (size_t)row*1024 + t*4) = o4;
}

// ---------------- launcher ----------------------------------------------------
extern "C" void kernel_launch(void* const* d_in, const int* in_sizes, int n_in,
                              void* d_out, int out_size, void* d_ws, size_t ws_size,
                              hipStream_t stream) {
  const float* x      = (const float*)d_in[0];
  const float* xf     = (const float*)d_in[1];
  const float* emb    = (const float*)d_in[2];
  const int*   cond   = (const int*)d_in[4];
  const float* ln_x_g = (const float*)d_in[5];
  const float* ln_x_b = (const float*)d_in[6];
  const float* ln_t_g = (const float*)d_in[7];
  const float* ln_t_b = (const float*)d_in[8];
  const float* Wq     = (const float*)d_in[9];
  const float* bq     = (const float*)d_in[10];
  const float* Wk     = (const float*)d_in[11];
  const float* bk     = (const float*)d_in[12];
  const float* Wv     = (const float*)d_in[13];
  const float* bv     = (const float*)d_in[14];
  const float* We     = (const float*)d_in[15];
  const float* be     = (const float*)d_in[16];
  const float* ln_y_g = (const float*)d_in[17];
  const float* ln_y_b = (const float*)d_in[18];
  const float* Wo     = (const float*)d_in[19];
  const float* bo     = (const float*)d_in[20];
  float* out = (float*)d_out;

  unsigned char* ws = (unsigned char*)d_ws;
  size_t off = 0;
  auto take = [&](size_t n){ unsigned char* p = ws + off; off += (n + 255) & ~(size_t)255; return p; };
  unsigned char* r1   = take(67108864);   // xln bf16 -> (epart) -> h bf16
  unsigned char* qb   = take(67108864);   // q bf16 -> y bf16 (in place)
  unsigned char* xfn  = take(12582912);   // LN(xf) bf16
  unsigned char* kb   = take(16777216);   // k bf16 [8192][1024]
  unsigned char* vtb  = take(16777216);   // v^T pre-swizzled bf16
  unsigned char* wqt  = take(2097152);
  unsigned char* wkvt = take(3145728);    // [2048][768] bf16
  unsigned char* wot  = take(2097152);
  unsigned char* eo   = take(262144);
  unsigned char* bkv  = take(8192);
  float* epart = (float*)r1;              // aliases r1; used after gemmQ consumed xln

  dim3 blk(256);
  dim3 blk512(512);
  // prep: all weights + bias concat (3592 blocks)
  prep<<<3592, blk, 0, stream>>>(Wq, Wk, Wv, Wo, bk, bv,
      (unsigned short*)wqt, (unsigned short*)wkvt, (unsigned short*)wot, (float*)bkv);
  // layernorms (x: 32768 rows, xf: 8192 rows)
  ln_all<<<40960, blk, 0, stream>>>(x, xf, ln_x_g, ln_x_b, ln_t_g, ln_t_b,
      (unsigned short*)r1, (unsigned short*)xfn);
  // Q projection
  gemm256<0><<<512, blk512, 0, stream>>>(r1, wqt, bq, qb, nullptr, nullptr, 32768, 1024, 1024, 2);
  // fused K/V projection: K -> kb, V -> swizzled vt directly
  gemm256<2><<<256, blk512, 0, stream>>>(xfn, wkvt, (const float*)bkv, kb, nullptr, vtb, 8192, 2048, 768, 3);
  // emb path
  embgemm<<<dim3(8,16), blk, 0, stream>>>(emb, We, epart);
  embred<<<256, blk, 0, stream>>>(epart, be, (float*)eo);
  // attention: y bf16 in place over q
  attn64<<<8192, blk, 0, stream>>>(qb, kb, 2048, vtb, cond, (unsigned short*)qb);
  // stylization -> h bf16 (overwrites r1)
  styl<<<32768, blk, 0, stream>>>((const unsigned short*)qb, ln_y_g, ln_y_b, (const float*)eo, (unsigned short*)r1);
  // output projection + residual
  gemm256<1><<<512, blk512, 0, stream>>>(r1, wot, bo, out, x, nullptr, 32768, 1024, 1024, 2);
}

// Round 7
// 462.365 us; speedup vs baseline: 1.0724x; 1.0156x over previous
//
#include <hip/hip_runtime.h>
#include <hip/hip_bf16.h>

#define DEV __device__ __forceinline__

typedef __attribute__((ext_vector_type(8))) short bf16x8;
typedef __attribute__((ext_vector_type(4))) float f32x4;
typedef __attribute__((ext_vector_type(8))) unsigned short u16x8;

DEV unsigned short f2bf(float f){
  unsigned int b = __float_as_uint(f);
  return (unsigned short)((b + 0x7fffu + ((b >> 16) & 1u)) >> 16);
}
DEV float bf2f(unsigned short u){ return __uint_as_float(((unsigned int)u)<<16); }

DEV float silu_f(float v){ return v / (1.f + __expf(-v)); }

DEV void gl_lds16(const void* g, void* l){
  __builtin_amdgcn_global_load_lds((const __attribute__((address_space(1))) void*)g,
                                   (__attribute__((address_space(3))) void*)l, 16, 0, 0);
}

// ---------- fused prep (weight convert/transpose + bias concat) + LayerNorms ---
// ids [0, 40960): LN rows (x: 0..32767, xf: 32768..40959)
// ids [40960, 44552): weight tiles + bias concat
DEV void wtile(const float* W, unsigned short* Wt, int K, int N, int nt, int kt, int tid,
               float (*tile)[33])
{
  int n0 = nt<<5, k0 = kt<<5;
  int tx = tid & 31, ty = tid >> 5;
  #pragma unroll
  for (int i=0;i<4;i++)
    tile[ty + i*8][tx] = W[(size_t)(k0 + ty + i*8)*N + n0 + tx];
  __syncthreads();
  #pragma unroll
  for (int i=0;i<4;i++)
    Wt[(size_t)(n0 + ty + i*8)*K + k0 + tx] = f2bf(tile[tx][ty + i*8]);
}

__global__ __launch_bounds__(256) void prep_ln(
    const float* __restrict__ x, const float* __restrict__ xf,
    const float* __restrict__ gx, const float* __restrict__ bx_,
    const float* __restrict__ gt, const float* __restrict__ bt,
    unsigned short* __restrict__ ox, unsigned short* __restrict__ ot,
    const float* __restrict__ Wq, const float* __restrict__ Wk,
    const float* __restrict__ Wv, const float* __restrict__ Wo,
    const float* __restrict__ bk, const float* __restrict__ bv,
    unsigned short* __restrict__ wqt, unsigned short* __restrict__ wkvt,
    unsigned short* __restrict__ wot, float* __restrict__ bkv)
{
  int row = blockIdx.x, t = threadIdx.x;
  if (row >= 40960){
    __shared__ float tile[32][33];
    int id = row - 40960;
    if (id < 8){
      int i = id*256 + t;
      bkv[i] = (i < 1024) ? bk[i] : bv[i-1024];
      return;
    }
    id -= 8;
    if (id < 1024){ wtile(Wq, wqt, 1024, 1024, id & 31, id >> 5, t, tile); return; }
    id -= 1024;
    if (id < 768){ wtile(Wk, wkvt, 768, 1024, id & 31, id >> 5, t, tile); return; }
    id -= 768;
    if (id < 768){ wtile(Wv, wkvt + (size_t)1024*768, 768, 1024, id & 31, id >> 5, t, tile); return; }
    id -= 768;
    wtile(Wo, wot, 1024, 1024, id & 31, id >> 5, t, tile);
    return;
  }
  const float* src; const float* g; const float* bb; unsigned short* out;
  int D, nvec;
  if (row < 32768){ src = x + (size_t)row*1024; g = gx; bb = bx_; out = ox + (size_t)row*1024; D = 1024; nvec = 256; }
  else { int r2 = row - 32768; src = xf + (size_t)r2*768; g = gt; bb = bt; out = ot + (size_t)r2*768; D = 768; nvec = 192; }
  float4 v = make_float4(0.f,0.f,0.f,0.f);
  if (t < nvec) v = ((const float4*)src)[t];
  float s  = v.x+v.y+v.z+v.w;
  float s2 = v.x*v.x+v.y*v.y+v.z*v.z+v.w*v.w;
  #pragma unroll
  for (int o=32;o;o>>=1){ s += __shfl_down(s,o,64); s2 += __shfl_down(s2,o,64); }
  __shared__ float red[8];
  if ((t&63)==0){ red[t>>6]=s; red[4+(t>>6)]=s2; }
  __syncthreads();
  float fs  = red[0]+red[1]+red[2]+red[3];
  float fs2 = red[4]+red[5]+red[6]+red[7];
  float mean = fs / (float)D;
  float var  = fmaxf(fs2/(float)D - mean*mean, 0.f);
  float rstd = rsqrtf(var + 1e-5f);
  if (t < nvec){
    float4 gv = ((const float4*)g)[t];
    float4 bv4 = ((const float4*)bb)[t];
    ushort4 o4;
    o4.x = f2bf((v.x-mean)*rstd*gv.x + bv4.x);
    o4.y = f2bf((v.y-mean)*rstd*gv.y + bv4.y);
    o4.z = f2bf((v.z-mean)*rstd*gv.z + bv4.z);
    o4.w = f2bf((v.w-mean)*rstd*gv.w + bv4.w);
    *(ushort4*)(out + t*4) = o4;
  }
}

// ---------------- GEMM: C[M][N] = A[M][K]bf16 @ Wt[N][K]bf16^T + bias ----------
// Round-2 measured-best structure: 128x128 tile, BK=64, double-buffered 64KB LDS,
// 4 waves, XOR-swizzled LDS via pre-swizzled global source, XCD-chunked 1-D grid.
// EPI: 0 = bf16 C. 1 = fp32 C = Xadd + val. 2 = KV fused: N-tiles [0,1024) -> K
//      bf16 [M][1024]; N-tiles [1024,2048) -> V scattered into pre-swizzled vt.
template<int EPI>
__global__ __launch_bounds__(256,2) void gemm128(
  const unsigned char* __restrict__ A, const unsigned char* __restrict__ Wt,
  const float* __restrict__ bias, void* __restrict__ Cout,
  const float* __restrict__ Xadd, unsigned char* __restrict__ vt,
  int M, int N, int K, int gxshift)
{
  __shared__ __align__(16) unsigned char lds[65536];
  const int nwg = gridDim.x;
  const int chunk = nwg >> 3;
  const int wg = blockIdx.x;
  const int lg = (wg & 7) * chunk + (wg >> 3);
  const int bx = lg & ((1<<gxshift)-1);
  const int by = lg >> gxshift;
  const int tid = threadIdx.x, w = tid>>6, lane = tid&63;
  const int l15 = lane&15, lq = lane>>4;
  const int m0 = by<<7, n0 = bx<<7;
  const size_t K2 = (size_t)K<<1;
  const int KT = K>>6;
  const int wr = (w>>1)&1, wc = w&1;
  const int srow = lane>>3;
  const int scb  = (lane&7)<<4;

  f32x4 acc[4][4];
  f32x4 zero = {0.f,0.f,0.f,0.f};
  #pragma unroll
  for (int i=0;i<4;i++)
    #pragma unroll
    for (int j=0;j<4;j++) acc[i][j] = zero;

  auto stage = [&](int buf, int kt){
    unsigned char* ldsA = lds + buf*32768;
    const size_t kb = (size_t)kt<<7;
    #pragma unroll
    for (int inst=0; inst<4; ++inst){
      int base = w*1024 + inst*4096;
      int row  = (base>>7) + srow;
      int cs   = scb ^ ((row&7)<<4);
      gl_lds16(A  + (size_t)(m0+row)*K2 + kb + cs, ldsA + base);
      gl_lds16(Wt + (size_t)(n0+row)*K2 + kb + cs, ldsA + 16384 + base);
    }
  };

  stage(0, 0);
  __syncthreads();
  for (int kt=0; kt<KT; ++kt){
    if (kt+1 < KT) stage((kt+1)&1, kt+1);
    const unsigned char* ldsA = lds + (kt&1)*32768;
    const unsigned char* ldsB = ldsA + 16384;
    bf16x8 af[2][4], bfr[2][4];
    #pragma unroll
    for (int i=0;i<4;i++){
      int r = wr*64 + i*16 + l15;
      int rb = r<<7, sw = (r&7)<<4;
      af[0][i] = *(const bf16x8*)(ldsA + rb + ((lq*16) ^ sw));
      af[1][i] = *(const bf16x8*)(ldsA + rb + ((64 + lq*16) ^ sw));
    }
    #pragma unroll
    for (int j=0;j<4;j++){
      int r = wc*64 + j*16 + l15;
      int rb = r<<7, sw = (r&7)<<4;
      bfr[0][j] = *(const bf16x8*)(ldsB + rb + ((lq*16) ^ sw));
      bfr[1][j] = *(const bf16x8*)(ldsB + rb + ((64 + lq*16) ^ sw));
    }
    #pragma unroll
    for (int kc=0;kc<2;kc++)
      #pragma unroll
      for (int i=0;i<4;i++)
        #pragma unroll
        for (int j=0;j<4;j++)
          acc[i][j] = __builtin_amdgcn_mfma_f32_16x16x32_bf16(af[kc][i], bfr[kc][j], acc[i][j], 0,0,0);
    __syncthreads();
  }
  #pragma unroll
  for (int j=0;j<4;j++){
    int n = n0 + wc*64 + j*16 + l15;
    float bvs = bias[n];
    #pragma unroll
    for (int i=0;i<4;i++){
      int mb = m0 + wr*64 + i*16 + lq*4;
      #pragma unroll
      for (int r=0;r<4;r++){
        int m = mb + r;
        float val = acc[i][j][r] + bvs;
        if (EPI==0){
          ((unsigned short*)Cout)[(size_t)m*N + n] = f2bf(val);
        } else if (EPI==1){
          size_t idx = (size_t)m*N + n;
          ((float*)Cout)[idx] = Xadd[idx] + val;
        } else {
          if (n0 < 1024){
            ((unsigned short*)Cout)[(size_t)m*1024 + n] = f2bf(val);
          } else {
            int d  = (n-1024)&63;
            int hh = (n-1024)>>6;
            int bb_ = m>>8, nk = m&255;
            *(unsigned short*)(vt + ((size_t)(bb_*16+hh)<<15) + d*512
                + (((nk>>3)<<4) ^ ((d&7)<<4)) + ((nk&7)<<1)) = f2bf(val);
          }
        }
      }
    }
  }
}

// ---------------- fused cross-attention, one block per (b,h,t-tile of 64) -----
__global__ __launch_bounds__(256,2) void attn64(
  const unsigned char* __restrict__ qg, const unsigned char* __restrict__ kg,
  int kstride, const unsigned char* __restrict__ vtg, const int* __restrict__ cond,
  unsigned short* __restrict__ yout)
{
  __shared__ __align__(16) unsigned char lds[73728];
  const int wg = blockIdx.x;
  const int lg = (wg & 7) * 1024 + (wg >> 3);
  const int t0 = (lg & 15) * 64;
  const int h  = (lg >> 4) & 15;
  const int b  = lg >> 8;
  const int tid = threadIdx.x, w = tid>>6, lane = tid&63;
  const int l15 = lane&15, lq = lane>>4;

  const unsigned char* kbase = kg + (size_t)b*256*kstride + (size_t)h*128;
  const unsigned char* vtb   = vtg + (size_t)(b*16+h)*32768;
  #pragma unroll
  for (int i=0;i<8;i++){
    int base = (w*8+i)*1024;
    int n  = (base>>7) + (lane>>3);
    int cb = (lane&7)<<4;
    gl_lds16(kbase + (size_t)n*kstride + (cb ^ ((n&7)<<4)), lds + base);
    gl_lds16(vtb + base + lane*16, lds + 32768 + base);
  }
  const unsigned char* qbase = qg + (size_t)(b*1024 + t0)*2048 + h*128;
  #pragma unroll
  for (int i=0;i<2;i++){
    int row = i*32 + (tid>>3);
    int cs  = ((tid&7)<<4) ^ ((row&7)<<4);
    gl_lds16(qbase + (size_t)row*2048 + cs, lds + 65536 + i*4096 + w*1024);
  }
  __syncthreads();

  const int qr = w*16 + l15;
  const int qsw = (qr&7)<<4;
  bf16x8 aq0 = *(const bf16x8*)(lds + 65536 + qr*128 + ((lq*16) ^ qsw));
  bf16x8 aq1 = *(const bf16x8*)(lds + 65536 + qr*128 + ((64 + lq*16) ^ qsw));

  f32x4 zero = {0.f,0.f,0.f,0.f};
  f32x4 s[16];
  #pragma unroll
  for (int nt=0;nt<16;nt++) s[nt] = zero;
  #pragma unroll
  for (int nt=0;nt<16;nt++){
    int n = nt*16 + l15;
    int rb = n<<7, sw = (n&7)<<4;
    bf16x8 kb0 = *(const bf16x8*)(lds + rb + ((lq*16) ^ sw));
    bf16x8 kb1 = *(const bf16x8*)(lds + rb + ((64 + lq*16) ^ sw));
    s[nt] = __builtin_amdgcn_mfma_f32_16x16x32_bf16(aq0, kb0, s[nt], 0,0,0);
    s[nt] = __builtin_amdgcn_mfma_f32_16x16x32_bf16(aq1, kb1, s[nt], 0,0,0);
  }
  #pragma unroll
  for (int r=0;r<4;r++){
    float m = s[0][r];
    #pragma unroll
    for (int nt=1;nt<16;nt++) m = fmaxf(m, s[nt][r]);
    m = fmaxf(m, __shfl_xor(m,1,64));
    m = fmaxf(m, __shfl_xor(m,2,64));
    m = fmaxf(m, __shfl_xor(m,4,64));
    m = fmaxf(m, __shfl_xor(m,8,64));
    float sum = 0.f;
    #pragma unroll
    for (int nt=0;nt<16;nt++){ float p = __expf(s[nt][r]-m); s[nt][r]=p; sum+=p; }
    sum += __shfl_xor(sum,1,64);
    sum += __shfl_xor(sum,2,64);
    sum += __shfl_xor(sum,4,64);
    sum += __shfl_xor(sum,8,64);
    float inv = 1.f/sum;
    #pragma unroll
    for (int nt=0;nt<16;nt++) s[nt][r] *= inv;
  }
  __syncthreads();
  #pragma unroll
  for (int nt=0;nt<16;nt++){
    int n = nt*16 + l15;
    int nb = (n>>3)<<4, nr = (n&7)<<1;
    #pragma unroll
    for (int r=0;r<4;r++){
      int tl = w*16 + lq*4 + r;
      *(unsigned short*)(lds + tl*512 + ((nb ^ ((tl&7)<<4)) | nr)) = f2bf(s[nt][r]);
    }
  }
  __syncthreads();
  f32x4 yv[4];
  #pragma unroll
  for (int dt=0;dt<4;dt++) yv[dt] = zero;
  const int tl = w*16 + l15;
  const int swp = (tl&7)<<4;
  #pragma unroll
  for (int kc=0;kc<8;kc++){
    bf16x8 pa = *(const bf16x8*)(lds + tl*512 + ((kc*64 + lq*16) ^ swp));
    #pragma unroll
    for (int dt=0;dt<4;dt++){
      int d = dt*16 + l15;
      bf16x8 vbv = *(const bf16x8*)(lds + 32768 + d*512 + ((kc*64 + lq*16) ^ ((d&7)<<4)));
      yv[dt] = __builtin_amdgcn_mfma_f32_16x16x32_bf16(pa, vbv, yv[dt], 0,0,0);
    }
  }
  float tc = (cond[b] % 10 > 0) ? 1.f : 0.f;
  #pragma unroll
  for (int dt=0;dt<4;dt++){
    #pragma unroll
    for (int r=0;r<4;r++){
      int tt = t0 + w*16 + lq*4 + r;
      yout[(size_t)(b*1024 + tt)*1024 + h*64 + dt*16 + l15] = f2bf(yv[dt][r]*tc);
    }
  }
}

// ---------------- emb GEMM + reduce -------------------------------------------
__global__ __launch_bounds__(256) void embgemm(const float* __restrict__ emb,
    const float* __restrict__ We, float* __restrict__ epart)
{
  __shared__ float a[32][128];
  int cb = blockIdx.x, ks = blockIdx.y, tid = threadIdx.x;
  int k0 = ks<<7;
  #pragma unroll
  for (int it=0; it<4; ++it){
    int fi = it*256 + tid;
    int r = fi>>5, c4 = (fi&31)<<2;
    float4 vv = *(const float4*)(emb + (size_t)r*2048 + k0 + c4);
    vv.x = silu_f(vv.x); vv.y = silu_f(vv.y); vv.z = silu_f(vv.z); vv.w = silu_f(vv.w);
    *(float4*)&a[r][c4] = vv;
  }
  __syncthreads();
  int c0 = (cb<<8) + tid;
  float acc[32];
  #pragma unroll
  for (int r=0;r<32;r++) acc[r]=0.f;
  for (int kk=0;kk<128;kk++){
    float wv = We[(size_t)(k0+kk)*2048 + c0];
    #pragma unroll
    for (int r=0;r<32;r++) acc[r] += a[r][kk]*wv;
  }
  #pragma unroll
  for (int r=0;r<32;r++) epart[(size_t)(ks*32 + r)*2048 + c0] = acc[r];
}

__global__ __launch_bounds__(256) void embred(const float* __restrict__ epart,
    const float* __restrict__ be, float* __restrict__ eo)
{
  int idx = blockIdx.x*256 + threadIdx.x;
  float s = be[idx & 2047];
  #pragma unroll
  for (int ks=0;ks<16;ks++) s += epart[(size_t)ks*65536 + idx];
  eo[idx] = s;
}

// ---------------- stylization --------------------------------------------------
__global__ __launch_bounds__(256) void styl(const unsigned short* __restrict__ y,
    const float* __restrict__ g, const float* __restrict__ bt,
    const float* __restrict__ eo, unsigned short* __restrict__ hout)
{
  int row = blockIdx.x, t = threadIdx.x, b = row>>10;
  ushort4 yv4 = ((const ushort4*)(y + (size_t)row*1024))[t];
  float in[4] = {bf2f(yv4.x), bf2f(yv4.y), bf2f(yv4.z), bf2f(yv4.w)};
  float s  = in[0]+in[1]+in[2]+in[3];
  float s2 = in[0]*in[0]+in[1]*in[1]+in[2]*in[2]+in[3]*in[3];
  #pragma unroll
  for (int o=32;o;o>>=1){ s += __shfl_down(s,o,64); s2 += __shfl_down(s2,o,64); }
  __shared__ float red[8];
  if ((t&63)==0){ red[t>>6]=s; red[4+(t>>6)]=s2; }
  __syncthreads();
  float fs  = red[0]+red[1]+red[2]+red[3];
  float fs2 = red[4]+red[5]+red[6]+red[7];
  float mean = fs*(1.f/1024.f);
  float var  = fmaxf(fs2*(1.f/1024.f) - mean*mean, 0.f);
  float rstd = rsqrtf(var + 1e-5f);
  float4 gv = ((const float4*)g)[t];
  float4 bv = ((const float4*)bt)[t];
  float4 sc = ((const float4*)(eo + (size_t)b*2048))[t];
  float4 sh = ((const float4*)(eo + (size_t)b*2048 + 1024))[t];
  float gg[4]  = {gv.x,gv.y,gv.z,gv.w};
  float bb[4]  = {bv.x,bv.y,bv.z,bv.w};
  float scs[4] = {sc.x,sc.y,sc.z,sc.w};
  float shs[4] = {sh.x,sh.y,sh.z,sh.w};
  unsigned short oo[4];
  #pragma unroll
  for (int c=0;c<4;c++){
    float hv = (in[c]-mean)*rstd*gg[c] + bb[c];
    hv = hv*(1.f+scs[c]) + shs[c];
    oo[c] = f2bf(silu_f(hv));
  }
  ushort4 o4; o4.x=oo[0]; o4.y=oo[1]; o4.z=oo[2]; o4.w=oo[3];
  *(ushort4*)(hout + (size_t)row*1024 + t*4) = o4;
}

// ---------------- launcher ----------------------------------------------------
extern "C" void kernel_launch(void* const* d_in, const int* in_sizes, int n_in,
                              void* d_out, int out_size, void* d_ws, size_t ws_size,
                              hipStream_t stream) {
  const float* x      = (const float*)d_in[0];
  const float* xf     = (const float*)d_in[1];
  const float* emb    = (const float*)d_in[2];
  const int*   cond   = (const int*)d_in[4];
  const float* ln_x_g = (const float*)d_in[5];
  const float* ln_x_b = (const float*)d_in[6];
  const float* ln_t_g = (const float*)d_in[7];
  const float* ln_t_b = (const float*)d_in[8];
  const float* Wq     = (const float*)d_in[9];
  const float* bq     = (const float*)d_in[10];
  const float* Wk     = (const float*)d_in[11];
  const float* bk     = (const float*)d_in[12];
  const float* Wv     = (const float*)d_in[13];
  const float* bv     = (const float*)d_in[14];
  const float* We     = (const float*)d_in[15];
  const float* be     = (const float*)d_in[16];
  const float* ln_y_g = (const float*)d_in[17];
  const float* ln_y_b = (const float*)d_in[18];
  const float* Wo     = (const float*)d_in[19];
  const float* bo     = (const float*)d_in[20];
  float* out = (float*)d_out;

  unsigned char* ws = (unsigned char*)d_ws;
  size_t off = 0;
  auto take = [&](size_t n){ unsigned char* p = ws + off; off += (n + 255) & ~(size_t)255; return p; };
  unsigned char* r1   = take(67108864);   // xln bf16 -> (epart) -> h bf16
  unsigned char* qb   = take(67108864);   // q bf16 -> y bf16 (in place)
  unsigned char* xfn  = take(12582912);   // LN(xf) bf16
  unsigned char* kb   = take(16777216);   // k bf16 [8192][1024]
  unsigned char* vtb  = take(16777216);   // v^T pre-swizzled bf16
  unsigned char* wqt  = take(2097152);
  unsigned char* wkvt = take(3145728);    // [2048][768] bf16
  unsigned char* wot  = take(2097152);
  unsigned char* eo   = take(262144);
  unsigned char* bkv  = take(8192);
  float* epart = (float*)r1;              // aliases r1; used after gemmQ consumed xln

  dim3 blk(256);
  // fused LN + weight prep (44552 blocks)
  prep_ln<<<44552, blk, 0, stream>>>(x, xf, ln_x_g, ln_x_b, ln_t_g, ln_t_b,
      (unsigned short*)r1, (unsigned short*)xfn,
      Wq, Wk, Wv, Wo, bk, bv,
      (unsigned short*)wqt, (unsigned short*)wkvt, (unsigned short*)wot, (float*)bkv);
  // Q projection (round-2 best GEMM structure)
  gemm128<0><<<2048, blk, 0, stream>>>(r1, wqt, bq, qb, nullptr, nullptr, 32768, 1024, 1024, 3);
  // fused K/V projection: K -> kb, V -> swizzled vt directly
  gemm128<2><<<1024, blk, 0, stream>>>(xfn, wkvt, (const float*)bkv, kb, nullptr, vtb, 8192, 2048, 768, 4);
  // emb path (epart aliases r1; runs after Q-GEMM consumed xln)
  embgemm<<<dim3(8,16), blk, 0, stream>>>(emb, We, epart);
  embred<<<256, blk, 0, stream>>>(epart, be, (float*)eo);
  // attention: y bf16 in place over q
  attn64<<<8192, blk, 0, stream>>>(qb, kb, 2048, vtb, cond, (unsigned short*)qb);
  // stylization -> h bf16 (overwrites r1)
  styl<<<32768, blk, 0, stream>>>((const unsigned short*)qb, ln_y_g, ln_y_b, (const float*)eo, (unsigned short*)r1);
  // output projection + residual
  gemm128<1><<<2048, blk, 0, stream>>>(r1, wot, bo, out, x, nullptr, 32768, 1024, 1024, 3);
}